// Round 9
// baseline (193.209 us; speedup 1.0000x reference)
//
#include <hip/hip_runtime.h>
#include <math.h>

#define N_VOX (96*96*96)        // 884736 voxels per volume
#define NVOL 8                  // 4 pred + 4 target volumes
#define NEL (4*N_VOX)           // 3538944 elements in pred/target
#define PLANE (96*96)           // 9216

// tile geometry for local CCL: full d-span x TW x TH
#define TW 8
#define TH 8
#define TILES_W 12
#define TILES_H 12
#define TILE_VOX (96*TW*TH)     // 6144
#define TILE_WORDS (TILE_VOX/32) // 192
#define MAXRUNS 3072            // max d-runs per tile (64 lines x 48)

#define NBPLANES 11             // interior tile boundaries per axis
#define NPAIRS (2*NBPLANES)     // 22 boundary plane-pairs per volume
#define FACES_PER_VOL (2*NPAIRS*PLANE) // 405504 ushorts
#define FALLR 65536             // dense UF capacity per volume (ushort ID space)
#define HT2N 4096               // per-plane dedup hash entries (16 KB LDS)
#define MAX_PROBES 16

// workspace header layout (4 KB, zeroed once). Per-volume counters strided
// to 128 B (round-4 lesson: same-line cross-XCD atomics serialize ~5ns each).
#define WS_ACC   0
#define WS_ROOT  256            // int, volume v at int-index (v<<5)
#define WS_EVT   1536           // int, volume v at int-index (v<<5)
#define WS_HDR   4096

// ---------------------------------------------------------------------------
// GLOBAL dense union-find. Labels only decrease (atomicMin) -> monotone.
// Cross-XCD safety: plain reads may be stale (stale = larger/older), but the
// merge loop advances on ATOMIC return values, which are authoritative; the
// l3==l1 event count is exact (atomicity -> unique destroyer per self-loop).
__device__ __forceinline__ int uf_find(int* __restrict__ L, int x) {
    int r = x;
    int p = L[r];
    while (p != r) { r = p; p = L[r]; }
    if (r != x) atomicMin(&L[x], r);     // path compression (monotone-safe)
    return r;
}

// returns # destroyed self-loops (exact union events).
__device__ __forceinline__ int uf_merge(int* __restrict__ L, int l1, int l2) {
    int ev = 0;
    while (l1 != l2) {
        if (l1 < l2) { int t = l1; l1 = l2; l2 = t; }   // l1 > l2
        int l3 = atomicMin(&L[l1], l2);
        if (l3 == l1) { ev++; l1 = l2; }
        else l1 = l3;
    }
    return ev;
}

// merge on LDS run labels
__device__ __forceinline__ void merge_local(int* lab, int l1, int l2) {
    while (l1 != l2 && l1 != lab[l1]) l1 = lab[l1];
    while (l1 != l2 && l2 != lab[l2]) l2 = lab[l2];
    while (l1 != l2) {
        if (l1 < l2) { int t = l1; l1 = l2; l2 = t; }
        int l3 = atomicMin(&lab[l1], l2);
        l1 = (l3 == l1) ? l2 : l3;
    }
}

// run ID (0-based, tile-global) of the run containing fg voxel i:
// rank = (#run-starts at positions <= i) - 1. Lines are word-aligned
// (96 = 3x32) so a global word-ordered prefix is line-consistent.
__device__ __forceinline__ int rrank(const unsigned* __restrict__ sm,
                                     const int* __restrict__ wpf, int i) {
    int w = i >> 5, b = i & 31;
    unsigned mask = (2u << b) - 1u;      // bits 0..b inclusive (b=31 -> all)
    return wpf[w] + __popc(sm[w] & mask) - 1;
}

// ---------------------------------------------------------------------------
// Phase 1: RUN-SPACE per-tile CCL in LDS (round-8 verified). Roots get DENSE
// per-volume IDs; NEW: each block also identity-inits its contiguous ID range
// of the per-volume global dense UF (gfall) -- free contiguous writes.
// Outputs: ushort face arrays + rootcnt + gfall identity + focal partial.
__global__ __launch_bounds__(256) void ccl_local(const float* __restrict__ pred,
                                                 const float* __restrict__ targ,
                                                 unsigned short* __restrict__ faces,
                                                 int* __restrict__ gfall,
                                                 int* __restrict__ rootcnt,
                                                 float* __restrict__ acc,
                                                 int vbase) {
    __shared__ int      lab[MAXRUNS];        // 12 KB run union-find
    __shared__ unsigned fm[TILE_WORDS];      // 768 B fg bits
    __shared__ unsigned sm[TILE_WORDS];      // 768 B run-start bits
    __shared__ int      wpf[TILE_WORDS];     // 768 B exclusive start prefix
    __shared__ float fws[4];
    __shared__ int   iws[4];
    __shared__ int   gbase;

    int vloc = blockIdx.y;
    int v = vbase + vloc;
    int tile = blockIdx.x;                   // 0..143
    int tw = tile % TILES_W, th = tile / TILES_W;
    int w0 = tw * TW, h0 = th * TH;
    int tbase = h0 * PLANE + w0 * 96;        // global index of tile origin
    unsigned short* Fw = faces + (size_t)vloc * FACES_PER_VOL;  // [b][side][h*96+d]
    unsigned short* Fh = Fw + 2 * NBPLANES * PLANE;             // [b][side][w*96+d]
    int* Gv = gfall + (size_t)vloc * FALLR;

    // ---- load: fg bits via ballot; fast focal partial for pred volumes ----
    float fsum = 0.0f;
    for (int it = 0; it < TILE_VOX / 256; it++) {
        int i = it * 256 + threadIdx.x;
        int lh = i / 768;                    // i = lh*768 + lw*96 + d
        int j = tbase + i + lh * 8448;       // global voxel index
        bool f;
        if (v < 4) {
            float xv = pred[(size_t)v * N_VOX + j];
            float tv = targ[(size_t)v * N_VOX + j];
            f = xv > 0.0f;                   // sigmoid(x)>0.5 <=> x>0
            float m   = (tv == 1.0f) ? -xv : xv;
            float at  = (tv == 1.0f) ? 0.25f : 0.75f;
            float e   = __expf(-fabsf(m));
            float inv = 1.0f / (1.0f + e);
            float sig = inv * ((m >= 0.0f) ? 1.0f : e);    // sigmoid(m)
            float sp  = fmaxf(m, 0.0f) + __logf(1.0f + e); // softplus(m)
            fsum += at * sig * sig * sp;
        } else {
            f = targ[(size_t)(v - 4) * N_VOX + j] > 0.5f;
        }
        unsigned long long bal = __ballot(f);
        if ((threadIdx.x & 63) == 0) {
            fm[i >> 5]       = (unsigned)bal;
            fm[(i >> 5) + 1] = (unsigned)(bal >> 32);
        }
    }
    __syncthreads();

    // ---- A: start masks + block scan -> run ranks; init run labels ----
    int cnt = 0;
    {
        unsigned st = 0;
        if (threadIdx.x < TILE_WORDS) {
            unsigned m = fm[threadIdx.x];
            unsigned carry = (threadIdx.x % 3) ? (fm[threadIdx.x - 1] >> 31) : 0u;
            st = m & ~((m << 1) | carry);
            sm[threadIdx.x] = st;
            cnt = __popc(st);
        }
    }
    int inc = cnt;
    for (int off = 1; off < 64; off <<= 1) {
        int u = __shfl_up(inc, off, 64);
        if ((threadIdx.x & 63) >= off) inc += u;
    }
    int wid = threadIdx.x >> 6;
    if ((threadIdx.x & 63) == 63) iws[wid] = inc;
    for (int r = threadIdx.x; r < MAXRUNS; r += 256) lab[r] = r;
    __syncthreads();
    int woff = 0;
    for (int k = 0; k < wid; k++) woff += iws[k];
    if (threadIdx.x < TILE_WORDS) wpf[threadIdx.x] = woff + inc - cnt;
    int Nr = iws[0] + iws[1] + iws[2];       // total runs (wave 3 adds none)
    __syncthreads();

    // ---- B: merge overlap-segment starts, w then h direction ----
    for (int t = threadIdx.x; t < 336; t += 256) {
        bool wdirn = t < 168;
        int tt = wdirn ? t : t - 168;
        int lh, lw, k;
        if (wdirn) { lh = tt / 21; int rem = tt % 21; lw = rem / 3; k = rem % 3; }
        else       { lh = tt / 24; int rem = tt % 24; lw = rem / 3; k = rem % 3; }
        int wb = (lh * 8 + lw) * 3 + k;
        int nb = wb + (wdirn ? 3 : 24);
        unsigned ov = fm[wb] & fm[nb];
        if (!ov) continue;
        unsigned carry = (k > 0) ? ((fm[wb - 1] & fm[nb - 1]) >> 31) : 0u;
        unsigned starts = ov & ~((ov << 1) | carry);
        int base_i = wb << 5;
        int dir = wdirn ? 96 : 768;
        while (starts) {
            int b = __builtin_ctz(starts);
            starts &= starts - 1;
            int i = base_i + b;
            merge_local(lab, rrank(sm, wpf, i), rrank(sm, wpf, i + dir));
        }
    }
    __syncthreads();

    // ---- C: count roots, dense-ID assign + global UF identity init ----
    int myroots = 0;
    for (int r = threadIdx.x; r < Nr; r += 256)
        if (lab[r] == r) myroots++;
    int s = myroots;
    for (int off = 1; off < 64; off <<= 1) {
        int u = __shfl_up(s, off, 64);
        if ((threadIdx.x & 63) >= off) s += u;
    }
    if ((threadIdx.x & 63) == 63) iws[wid] = s;
    __syncthreads();
    int wbase = 0;
    for (int k = 0; k < wid; k++) wbase += iws[k];
    if (threadIdx.x == 0)
        gbase = atomicAdd(&rootcnt[v << 5], iws[0] + iws[1] + iws[2] + iws[3]);
    __syncthreads();
    int nid = gbase + wbase + (s - myroots);
    for (int r = threadIdx.x; r < Nr; r += 256)
        if (lab[r] == r) { Gv[nid] = nid; lab[r] = ~(nid++); }
    __syncthreads();

    // ---- D: flatten non-roots to ~denseID (monotone, race-safe) ----
    for (int r = threadIdx.x; r < Nr; r += 256) {
        int p = lab[r];
        if (p >= 0) {
            int q2 = lab[p];
            while (q2 >= 0) { p = q2; q2 = lab[p]; }
            lab[r] = q2;
        }
    }
    __syncthreads();

    // ---- E: resolve + store the 4 interior-adjacent faces (ushort4) ----
    for (int t = threadIdx.x; t < 768; t += 256) {
        int f  = t / 192;
        int g  = t % 192;
        int u  = g / 24;                     // row within face (lh or lw)
        int d4 = (g % 24) * 4;
        int i0; unsigned short* dst;
        if (f == 0) {
            if (tw == 0) continue;
            i0  = u * 768 + d4;
            dst = Fw + ((tw - 1) * 2 + 1) * PLANE + (h0 + u) * 96 + d4;
        } else if (f == 1) {
            if (tw == TILES_W - 1) continue;
            i0  = u * 768 + 7 * 96 + d4;
            dst = Fw + (tw * 2) * PLANE + (h0 + u) * 96 + d4;
        } else if (f == 2) {
            if (th == 0) continue;
            i0  = u * 96 + d4;
            dst = Fh + ((th - 1) * 2 + 1) * PLANE + (w0 + u) * 96 + d4;
        } else {
            if (th == TILES_H - 1) continue;
            i0  = 7 * 768 + u * 96 + d4;
            dst = Fh + (th * 2) * PLANE + (w0 + u) * 96 + d4;
        }
        unsigned mw = fm[i0 >> 5];           // bits d4..d4+3 in one word
        unsigned short vals[4];
        bool prevf = false;
        for (int q = 0; q < 4; q++) {
            bool fb = (mw >> ((d4 & 31) + q)) & 1;
            if (fb) vals[q] = prevf ? vals[q - 1]
                                    : (unsigned short)(~lab[rrank(sm, wpf, i0 + q)]);
            else vals[q] = 0xFFFFu;
            prevf = fb;
        }
        *(ushort4*)dst = make_ushort4(vals[0], vals[1], vals[2], vals[3]);
    }

    // ---- wave-shuffle reduction: focal partial ----
    for (int off = 32; off; off >>= 1) fsum += __shfl_down(fsum, off, 64);
    if ((threadIdx.x & 63) == 0) fws[wid] = fsum;
    __syncthreads();
    if (threadIdx.x == 0) {
        float ft = fws[0] + fws[1] + fws[2] + fws[3];
        if (v < 4 && ft != 0.0f) atomicAdd(acc, ft);
    }
}

// ---------------------------------------------------------------------------
// Phase 2 (fused): one block per (plane-pair, volume) = 22 x nv blocks.
// Stream plane coalesced -> extract overlap-segment-start (a,b) pairs ->
// dedup via private 16 KB LDS hash (~5x atomic reduction) -> merge DIRECTLY
// into the per-volume global dense UF (gfall, ~60 KB live, L2-resident) with
// exact event counting. Replaces the pairs-spill + narrow 8-block union
// (round-8 lesson: that pair cost ~95 us at 3% machine utilization).
// Per-volume UF regions are 256 KB apart -> no cross-volume line sharing.
__global__ __launch_bounds__(256) void ccl_merge(const unsigned short* __restrict__ faces,
                                                 int* __restrict__ gfall,
                                                 int* __restrict__ events,
                                                 int vbase) {
    __shared__ unsigned ht[HT2N];            // 16 KB dedup hash
    __shared__ int wsum[4];
    for (int i = threadIdx.x; i < HT2N; i += 256) ht[i] = 0xFFFFFFFFu;
    __syncthreads();

    int f    = blockIdx.x;                   // plane pair 0..21
    int vloc = blockIdx.y;
    int v    = vbase + vloc;
    const unsigned short* A = faces + (size_t)vloc * FACES_PER_VOL
                                    + (size_t)(2 * f) * PLANE;
    const unsigned short* B = A + PLANE;
    int* L = gfall + (size_t)vloc * FALLR;

    int ev = 0;
    const int GPP = PLANE / 8;               // 1152 8-wide groups
    for (int g = threadIdx.x; g < GPP; g += 256) {
        int e8 = g * 8;
        int4 aw = *(const int4*)(A + e8);    // 8 ushorts, coalesced 16B
        int4 bw = *(const int4*)(B + e8);
        unsigned a32[4] = {(unsigned)aw.x, (unsigned)aw.y, (unsigned)aw.z, (unsigned)aw.w};
        unsigned b32[4] = {(unsigned)bw.x, (unsigned)bw.y, (unsigned)bw.z, (unsigned)bw.w};
        bool pf = false;
        if (e8 % 96) pf = (A[e8 - 1] != 0xFFFFu) && (B[e8 - 1] != 0xFFFFu);
        #pragma unroll
        for (int q = 0; q < 8; q++) {
            unsigned av = (a32[q >> 1] >> ((q & 1) * 16)) & 0xFFFFu;
            unsigned bv = (b32[q >> 1] >> ((q & 1) * 16)) & 0xFFFFu;
            bool f2 = (av != 0xFFFFu) && (bv != 0xFFFFu);
            if (f2 && !pf && av != bv) {     // overlap-segment start along d
                unsigned lo = av < bv ? av : bv;
                unsigned hi = av < bv ? bv : av;
                unsigned key = (lo << 16) | hi;
                unsigned h = (key * 2654435761u) >> 20;   // -> 12-bit slot
                bool fresh = false;
                for (int pr = 0; pr < MAX_PROBES; pr++) {
                    unsigned prev = atomicCAS(&ht[h], 0xFFFFFFFFu, key);
                    if (prev == 0xFFFFFFFFu) { fresh = true; break; }
                    if (prev == key) break;
                    h = (h + 1) & (HT2N - 1);
                    if (pr == MAX_PROBES - 1) fresh = true;  // cap: dupe ok
                }
                if (fresh) {                 // merge into global dense UF
                    int ra = uf_find(L, (int)lo);
                    int rb = uf_find(L, (int)hi);
                    if (ra != rb) ev += uf_merge(L, ra, rb);
                }
            }
            pf = f2;
        }
    }

    // block reduction of union events -> one global atomicAdd per block
    for (int off = 32; off; off >>= 1) ev += __shfl_down(ev, off, 64);
    if ((threadIdx.x & 63) == 0) wsum[threadIdx.x >> 6] = ev;
    __syncthreads();
    if (threadIdx.x == 0) {
        int tot = wsum[0] + wsum[1] + wsum[2] + wsum[3];
        if (tot) atomicAdd(&events[v << 5], tot);
    }
}

// ---------------------------------------------------------------------------
// components[v] = rootcnt[v] - events[v]
__global__ void finalize_kernel(const float* __restrict__ acc,
                                const int* __restrict__ rootcnt,
                                const int* __restrict__ events,
                                float* __restrict__ out) {
    float focal = acc[0] / (float)NEL;
    float c[NVOL];
    for (int v = 0; v < NVOL; v++)
        c[v] = (float)(rootcnt[v << 5] - events[v << 5]);
    float dp0 = 0.5f * (c[0] + c[2]);
    float dp1 = 0.5f * (c[1] + c[3]);
    float dt0 = 0.5f * (c[4] + c[6]);
    float dt1 = 0.5f * (c[5] + c[7]);
    float topo = 0.5f * (fabsf(dp0 - dt0) + fabsf(dp1 - dt1));
    out[0] = focal + 0.1f * topo;
}

// ---------------------------------------------------------------------------
extern "C" void kernel_launch(void* const* d_in, const int* in_sizes, int n_in,
                              void* d_out, int out_size, void* d_ws, size_t ws_size,
                              hipStream_t stream) {
    const float* pred = (const float*)d_in[0];
    const float* targ = (const float*)d_in[1];
    float* out = (float*)d_out;

    // header (4 KB, zeroed; per-volume counters strided to 128 B)
    float* acc     = (float*)((char*)d_ws + WS_ACC);
    int*   rootcnt = (int*)((char*)d_ws + WS_ROOT);
    int*   events  = (int*)((char*)d_ws + WS_EVT);
    unsigned short* faces = (unsigned short*)((char*)d_ws + WS_HDR);

    size_t per_vol = (size_t)FACES_PER_VOL * 2 + (size_t)FALLR * 4;
    size_t avail   = (ws_size > WS_HDR) ? ws_size - WS_HDR : 0;
    int vols_per_pass = (int)(avail / per_vol);
    if (vols_per_pass > NVOL) vols_per_pass = NVOL;
    if (vols_per_pass < 1) vols_per_pass = 1;
    int* gfall = (int*)(faces + (size_t)vols_per_pass * FACES_PER_VOL);

    hipMemsetAsync(d_ws, 0, WS_HDR, stream);

    for (int vbase = 0; vbase < NVOL; vbase += vols_per_pass) {
        int nv = NVOL - vbase;
        if (nv > vols_per_pass) nv = vols_per_pass;
        dim3 tgrid(TILES_W * TILES_H, nv);
        ccl_local<<<tgrid, dim3(256), 0, stream>>>(pred, targ, faces, gfall,
                                                   rootcnt, acc, vbase);
        dim3 mgrid(NPAIRS, nv);
        ccl_merge<<<mgrid, dim3(256), 0, stream>>>(faces, gfall, events, vbase);
    }

    finalize_kernel<<<1, 1, 0, stream>>>(acc, rootcnt, events, out);
}

// Round 10
// 151.903 us; speedup vs baseline: 1.2719x; 1.2719x over previous
//
#include <hip/hip_runtime.h>
#include <math.h>

#define N_VOX (96*96*96)        // 884736 voxels per volume
#define NVOL 8                  // 4 pred + 4 target volumes
#define NEL (4*N_VOX)           // 3538944 elements in pred/target
#define PLANE (96*96)           // 9216

// tile geometry for local CCL: full d-span x TW x TH
#define TW 8
#define TH 8
#define TILES_W 12
#define TILES_H 12
#define TILE_VOX (96*TW*TH)     // 6144
#define TILE_WORDS (TILE_VOX/32) // 192
#define MAXRUNS 3072            // max d-runs per tile (64 lines x 48)

#define NBPLANES 11             // interior tile boundaries per axis
#define NPAIRS (2*NBPLANES)     // 22 boundary plane-pairs per volume
#define FACES_PER_VOL (2*NPAIRS*PLANE) // 405504 ushorts
#define MAXR 40192              // dense roots that fit in 157 KB LDS
#define FALLR 65536             // global fallback capacity (ushort ID space)
#define SEGCAP 4608             // hard bound: <=48 starts/line * 96 lines/plane
#define HT2N 4096               // per-plane dedup hash entries (16 KB of slab)
#define MAX_PROBES 16

// workspace header (8 KB, zeroed once). Per-volume counters strided to 128 B
// (round-4 lesson: same-line cross-XCD atomics serialize ~5ns each).
// ROUND-9 LESSON (3rd confirmation): union-find with hot roots in GLOBAL
// memory serializes cross-XCD (r1=79us, r4=258us, r9=75us) -> UF stays in LDS.
#define WS_ACC   0
#define WS_ROOT  256            // int, volume v at byte 256+v*128
#define WS_COMP  1536           // int, volume v at byte 1536+v*128
#define WS_DONE  2816           // int, volume v at byte 2816+v*128
#define WS_VDONE 3840           // int
#define WS_PCNT  4096           // int [v*NPAIRS + f]
#define WS_HDR   8192

// ---------------------------------------------------------------------------
// union-find on LDS (or gfall fallback). Labels only decrease (atomicMin).
__device__ __forceinline__ int uf_find(int* __restrict__ L, int x) {
    int r = x;
    int p = L[r];
    while (p != r) { r = p; p = L[r]; }
    if (r != x) atomicMin(&L[x], r);     // path compression (monotone-safe)
    return r;
}

// returns # destroyed self-loops (exact union events).
__device__ __forceinline__ int uf_merge(int* __restrict__ L, int l1, int l2) {
    int ev = 0;
    while (l1 != l2) {
        if (l1 < l2) { int t = l1; l1 = l2; l2 = t; }   // l1 > l2
        int l3 = atomicMin(&L[l1], l2);
        if (l3 == l1) { ev++; l1 = l2; }
        else l1 = l3;
    }
    return ev;
}

// merge on LDS run labels
__device__ __forceinline__ void merge_local(int* lab, int l1, int l2) {
    while (l1 != l2 && l1 != lab[l1]) l1 = lab[l1];
    while (l1 != l2 && l2 != lab[l2]) l2 = lab[l2];
    while (l1 != l2) {
        if (l1 < l2) { int t = l1; l1 = l2; l2 = t; }
        int l3 = atomicMin(&lab[l1], l2);
        l1 = (l3 == l1) ? l2 : l3;
    }
}

// run ID (0-based, tile-global) of the run containing fg voxel i:
// rank = (#run-starts at positions <= i) - 1. Lines are word-aligned
// (96 = 3x32) so a global word-ordered prefix is line-consistent.
__device__ __forceinline__ int rrank(const unsigned* __restrict__ sm,
                                     const int* __restrict__ wpf, int i) {
    int w = i >> 5, b = i & 31;
    unsigned mask = (2u << b) - 1u;      // bits 0..b inclusive (b=31 -> all)
    return wpf[w] + __popc(sm[w] & mask) - 1;
}

// ---------------------------------------------------------------------------
// Phase 1: RUN-SPACE per-tile CCL in LDS (round-8 verified, 60us). Roots get
// DENSE per-volume IDs. Outputs ONLY ushort face arrays + rootcnt + focal.
__global__ __launch_bounds__(256) void ccl_local(const float* __restrict__ pred,
                                                 const float* __restrict__ targ,
                                                 unsigned short* __restrict__ faces,
                                                 int* __restrict__ rootcnt,
                                                 float* __restrict__ acc,
                                                 int vbase) {
    __shared__ int      lab[MAXRUNS];        // 12 KB run union-find
    __shared__ unsigned fm[TILE_WORDS];      // 768 B fg bits
    __shared__ unsigned sm[TILE_WORDS];      // 768 B run-start bits
    __shared__ int      wpf[TILE_WORDS];     // 768 B exclusive start prefix
    __shared__ float fws[4];
    __shared__ int   iws[4];
    __shared__ int   gbase;

    int vloc = blockIdx.y;
    int v = vbase + vloc;
    int tile = blockIdx.x;                   // 0..143
    int tw = tile % TILES_W, th = tile / TILES_W;
    int w0 = tw * TW, h0 = th * TH;
    int tbase = h0 * PLANE + w0 * 96;        // global index of tile origin
    unsigned short* Fw = faces + (size_t)vloc * FACES_PER_VOL;  // [b][side][h*96+d]
    unsigned short* Fh = Fw + 2 * NBPLANES * PLANE;             // [b][side][w*96+d]

    // ---- load: fg bits via ballot; fast focal partial for pred volumes ----
    float fsum = 0.0f;
    for (int it = 0; it < TILE_VOX / 256; it++) {
        int i = it * 256 + threadIdx.x;
        int lh = i / 768;                    // i = lh*768 + lw*96 + d
        int j = tbase + i + lh * 8448;       // global voxel index
        bool f;
        if (v < 4) {
            float xv = pred[(size_t)v * N_VOX + j];
            float tv = targ[(size_t)v * N_VOX + j];
            f = xv > 0.0f;                   // sigmoid(x)>0.5 <=> x>0
            float m   = (tv == 1.0f) ? -xv : xv;
            float at  = (tv == 1.0f) ? 0.25f : 0.75f;
            float e   = __expf(-fabsf(m));
            float inv = 1.0f / (1.0f + e);
            float sig = inv * ((m >= 0.0f) ? 1.0f : e);    // sigmoid(m)
            float sp  = fmaxf(m, 0.0f) + __logf(1.0f + e); // softplus(m)
            fsum += at * sig * sig * sp;
        } else {
            f = targ[(size_t)(v - 4) * N_VOX + j] > 0.5f;
        }
        unsigned long long bal = __ballot(f);
        if ((threadIdx.x & 63) == 0) {
            fm[i >> 5]       = (unsigned)bal;
            fm[(i >> 5) + 1] = (unsigned)(bal >> 32);
        }
    }
    __syncthreads();

    // ---- A: start masks + block scan -> run ranks; init run labels ----
    int cnt = 0;
    {
        unsigned st = 0;
        if (threadIdx.x < TILE_WORDS) {
            unsigned m = fm[threadIdx.x];
            unsigned carry = (threadIdx.x % 3) ? (fm[threadIdx.x - 1] >> 31) : 0u;
            st = m & ~((m << 1) | carry);
            sm[threadIdx.x] = st;
            cnt = __popc(st);
        }
    }
    int inc = cnt;
    for (int off = 1; off < 64; off <<= 1) {
        int u = __shfl_up(inc, off, 64);
        if ((threadIdx.x & 63) >= off) inc += u;
    }
    int wid = threadIdx.x >> 6;
    if ((threadIdx.x & 63) == 63) iws[wid] = inc;
    for (int r = threadIdx.x; r < MAXRUNS; r += 256) lab[r] = r;
    __syncthreads();
    int woff = 0;
    for (int k = 0; k < wid; k++) woff += iws[k];
    if (threadIdx.x < TILE_WORDS) wpf[threadIdx.x] = woff + inc - cnt;
    int Nr = iws[0] + iws[1] + iws[2];       // total runs (wave 3 adds none)
    __syncthreads();

    // ---- B: merge overlap-segment starts, w then h direction ----
    for (int t = threadIdx.x; t < 336; t += 256) {
        bool wdirn = t < 168;
        int tt = wdirn ? t : t - 168;
        int lh, lw, k;
        if (wdirn) { lh = tt / 21; int rem = tt % 21; lw = rem / 3; k = rem % 3; }
        else       { lh = tt / 24; int rem = tt % 24; lw = rem / 3; k = rem % 3; }
        int wb = (lh * 8 + lw) * 3 + k;
        int nb = wb + (wdirn ? 3 : 24);
        unsigned ov = fm[wb] & fm[nb];
        if (!ov) continue;
        unsigned carry = (k > 0) ? ((fm[wb - 1] & fm[nb - 1]) >> 31) : 0u;
        unsigned starts = ov & ~((ov << 1) | carry);
        int base_i = wb << 5;
        int dir = wdirn ? 96 : 768;
        while (starts) {
            int b = __builtin_ctz(starts);
            starts &= starts - 1;
            int i = base_i + b;
            merge_local(lab, rrank(sm, wpf, i), rrank(sm, wpf, i + dir));
        }
    }
    __syncthreads();

    // ---- C: count roots, dense-ID assign (full-lane strided run loops) ----
    int myroots = 0;
    for (int r = threadIdx.x; r < Nr; r += 256)
        if (lab[r] == r) myroots++;
    int s = myroots;
    for (int off = 1; off < 64; off <<= 1) {
        int u = __shfl_up(s, off, 64);
        if ((threadIdx.x & 63) >= off) s += u;
    }
    if ((threadIdx.x & 63) == 63) iws[wid] = s;
    __syncthreads();
    int wbase = 0;
    for (int k = 0; k < wid; k++) wbase += iws[k];
    if (threadIdx.x == 0)
        gbase = atomicAdd(&rootcnt[v << 5], iws[0] + iws[1] + iws[2] + iws[3]);
    __syncthreads();
    int nid = gbase + wbase + (s - myroots);
    for (int r = threadIdx.x; r < Nr; r += 256)
        if (lab[r] == r) lab[r] = ~(nid++);   // same iteration order as count
    __syncthreads();

    // ---- D: flatten non-roots to ~denseID (monotone, race-safe) ----
    for (int r = threadIdx.x; r < Nr; r += 256) {
        int p = lab[r];
        if (p >= 0) {
            int q2 = lab[p];
            while (q2 >= 0) { p = q2; q2 = lab[p]; }
            lab[r] = q2;
        }
    }
    __syncthreads();

    // ---- E: resolve + store the 4 interior-adjacent faces (ushort4) ----
    for (int t = threadIdx.x; t < 768; t += 256) {
        int f  = t / 192;
        int g  = t % 192;
        int u  = g / 24;                     // row within face (lh or lw)
        int d4 = (g % 24) * 4;
        int i0; unsigned short* dst;
        if (f == 0) {
            if (tw == 0) continue;
            i0  = u * 768 + d4;
            dst = Fw + ((tw - 1) * 2 + 1) * PLANE + (h0 + u) * 96 + d4;
        } else if (f == 1) {
            if (tw == TILES_W - 1) continue;
            i0  = u * 768 + 7 * 96 + d4;
            dst = Fw + (tw * 2) * PLANE + (h0 + u) * 96 + d4;
        } else if (f == 2) {
            if (th == 0) continue;
            i0  = u * 96 + d4;
            dst = Fh + ((th - 1) * 2 + 1) * PLANE + (w0 + u) * 96 + d4;
        } else {
            if (th == TILES_H - 1) continue;
            i0  = 7 * 768 + u * 96 + d4;
            dst = Fh + (th * 2) * PLANE + (w0 + u) * 96 + d4;
        }
        unsigned mw = fm[i0 >> 5];           // bits d4..d4+3 in one word
        unsigned short vals[4];
        bool prevf = false;
        for (int q = 0; q < 4; q++) {
            bool fb = (mw >> ((d4 & 31) + q)) & 1;
            if (fb) vals[q] = prevf ? vals[q - 1]
                                    : (unsigned short)(~lab[rrank(sm, wpf, i0 + q)]);
            else vals[q] = 0xFFFFu;
            prevf = fb;
        }
        *(ushort4*)dst = make_ushort4(vals[0], vals[1], vals[2], vals[3]);
    }

    // ---- wave-shuffle reduction: focal partial ----
    for (int off = 32; off; off >>= 1) fsum += __shfl_down(fsum, off, 64);
    if ((threadIdx.x & 63) == 0) fws[wid] = fsum;
    __syncthreads();
    if (threadIdx.x == 0) {
        float ft = fws[0] + fws[1] + fws[2] + fws[3];
        if (v < 4 && ft != 0.0f) atomicAdd(acc, ft);
    }
}

// ---------------------------------------------------------------------------
// Phase 2 (fused, last-block pattern): grid (22 planes x nv volumes), 1024 thr.
//  P) per-plane dedup: stream the plane coalesced, extract overlap-segment-
//     start pairs, dedup via LDS hash (first 16 KB of slab), write uniques to
//     this block's PRIVATE segment via an LDS counter (zero global atomics).
//  U) the 22nd-arriving block of each volume (device-side done-counter)
//     becomes the union block: acquire fence, reuse slab as the dense LDS UF,
//     process uniques with a FLATTENED index space (full-lane utilization),
//     exact event counting -> comp[v] = R - events.
//  F) the 8th volume to finish computes the final loss in-kernel.
// No spin-waits -> no deadlock; non-last blocks exit. Release/acquire via
// __threadfence() around the strided done counters (rocPRIM lookback pattern).
__global__ __launch_bounds__(1024) void ccl_bmerge(const unsigned short* __restrict__ faces,
                                                   unsigned* __restrict__ pairs,
                                                   int* __restrict__ pcnt,
                                                   int* __restrict__ gfall,
                                                   const int* __restrict__ rootcnt,
                                                   int* __restrict__ comp,
                                                   int* __restrict__ done,
                                                   int* __restrict__ vdone,
                                                   const float* __restrict__ acc,
                                                   float* __restrict__ out,
                                                   int vbase) {
    __shared__ int slab[MAXR];               // 157 KB: dedup hash, then UF
    __shared__ int offs[NPAIRS + 1];
    __shared__ int wsum[16];
    __shared__ int nloc, lastf, lastv;
    unsigned* ht = (unsigned*)slab;          // first HT2N entries

    int f    = blockIdx.x;                   // plane pair 0..21
    int vloc = blockIdx.y;
    int v    = vbase + vloc;
    const unsigned short* A = faces + (size_t)vloc * FACES_PER_VOL
                                    + (size_t)(2 * f) * PLANE;
    const unsigned short* B = A + PLANE;
    unsigned* pb = pairs + ((size_t)vloc * NPAIRS + f) * SEGCAP;

    // ---- P: dedup this plane's pairs ----
    for (int i = threadIdx.x; i < HT2N; i += 1024) ht[i] = 0xFFFFFFFFu;
    if (threadIdx.x == 0) nloc = 0;
    __syncthreads();

    const int GPP = PLANE / 8;               // 1152 8-wide groups
    for (int g = threadIdx.x; g < GPP; g += 1024) {
        int e8 = g * 8;
        int4 aw = *(const int4*)(A + e8);    // 8 ushorts, coalesced 16B
        int4 bw = *(const int4*)(B + e8);
        unsigned a32[4] = {(unsigned)aw.x, (unsigned)aw.y, (unsigned)aw.z, (unsigned)aw.w};
        unsigned b32[4] = {(unsigned)bw.x, (unsigned)bw.y, (unsigned)bw.z, (unsigned)bw.w};
        bool pf = false;
        if (e8 % 96) pf = (A[e8 - 1] != 0xFFFFu) && (B[e8 - 1] != 0xFFFFu);
        #pragma unroll
        for (int q = 0; q < 8; q++) {
            unsigned av = (a32[q >> 1] >> ((q & 1) * 16)) & 0xFFFFu;
            unsigned bv = (b32[q >> 1] >> ((q & 1) * 16)) & 0xFFFFu;
            bool f2 = (av != 0xFFFFu) && (bv != 0xFFFFu);
            if (f2 && !pf && av != bv) {     // overlap-segment start along d
                unsigned lo = av < bv ? av : bv;
                unsigned hi = av < bv ? bv : av;
                unsigned key = (lo << 16) | hi;
                unsigned h = (key * 2654435761u) >> 20;   // -> 12-bit slot
                bool fresh = false;
                for (int pr = 0; pr < MAX_PROBES; pr++) {
                    unsigned prev = atomicCAS(&ht[h], 0xFFFFFFFFu, key);
                    if (prev == 0xFFFFFFFFu) { fresh = true; break; }
                    if (prev == key) break;
                    h = (h + 1) & (HT2N - 1);
                    if (pr == MAX_PROBES - 1) fresh = true;  // cap: dupe ok
                }
                if (fresh) {
                    int ix = atomicAdd(&nloc, 1);    // LDS atomic, on-CU
                    pb[ix] = key;                    // ix < SEGCAP bound
                }
            }
            pf = f2;
        }
    }
    __syncthreads();
    if (threadIdx.x == 0) {
        pcnt[v * NPAIRS + f] = nloc;
        __threadfence();                     // release: segment + pcnt visible
        int old = atomicAdd(&done[v << 5], 1);
        lastf = (old == NPAIRS - 1);
    }
    __syncthreads();
    if (!lastf) return;                      // not the last plane of volume v

    // ---- U: union for volume v (this block saw all 22 segments) ----
    __threadfence();                         // acquire
    int R = rootcnt[v << 5];
    int* lab = (R <= MAXR) ? slab : (gfall + (size_t)vloc * FALLR);
    if (threadIdx.x == 0) {
        int o = 0;
        for (int k = 0; k < NPAIRS; k++) { offs[k] = o; o += pcnt[v * NPAIRS + k]; }
        offs[NPAIRS] = o;
    }
    __syncthreads();                         // ht region dead; safe to overwrite
    for (int i = threadIdx.x; i < R; i += 1024) lab[i] = i;
    int tot = offs[NPAIRS];
    __syncthreads();

    int ev = 0;
    for (int gi = threadIdx.x; gi < tot; gi += 1024) {
        int fi = 0;
        while (offs[fi + 1] <= gi) fi++;     // <=22 LDS reads, flattened space
        unsigned key = pairs[((size_t)vloc * NPAIRS + fi) * SEGCAP + (gi - offs[fi])];
        int a = (int)(key >> 16), b = (int)(key & 0xFFFFu);
        int ra = uf_find(lab, a);
        int rb = uf_find(lab, b);
        if (ra != rb) ev += uf_merge(lab, ra, rb);
    }

    for (int off = 32; off; off >>= 1) ev += __shfl_down(ev, off, 64);
    if ((threadIdx.x & 63) == 0) wsum[threadIdx.x >> 6] = ev;
    __syncthreads();
    if (threadIdx.x == 0) {
        int tote = 0;
        for (int k = 0; k < 16; k++) tote += wsum[k];
        comp[v << 5] = R - tote;             // components of volume v
        __threadfence();                     // release comp[v]
        int old2 = atomicAdd(vdone, 1);
        lastv = (old2 == NVOL - 1);
    }
    __syncthreads();
    if (!lastv) return;

    // ---- F: final loss (all NVOL comps + acc are now visible) ----
    if (threadIdx.x == 0) {
        __threadfence();                     // acquire
        float c[NVOL];
        for (int w = 0; w < NVOL; w++) c[w] = (float)comp[w << 5];
        float dp0 = 0.5f * (c[0] + c[2]);
        float dp1 = 0.5f * (c[1] + c[3]);
        float dt0 = 0.5f * (c[4] + c[6]);
        float dt1 = 0.5f * (c[5] + c[7]);
        float topo = 0.5f * (fabsf(dp0 - dt0) + fabsf(dp1 - dt1));
        out[0] = acc[0] / (float)NEL + 0.1f * topo;
    }
}

// ---------------------------------------------------------------------------
extern "C" void kernel_launch(void* const* d_in, const int* in_sizes, int n_in,
                              void* d_out, int out_size, void* d_ws, size_t ws_size,
                              hipStream_t stream) {
    const float* pred = (const float*)d_in[0];
    const float* targ = (const float*)d_in[1];
    float* out = (float*)d_out;

    // header (8 KB, zeroed; per-volume counters strided to 128 B)
    float* acc     = (float*)((char*)d_ws + WS_ACC);
    int*   rootcnt = (int*)((char*)d_ws + WS_ROOT);
    int*   comp    = (int*)((char*)d_ws + WS_COMP);
    int*   done    = (int*)((char*)d_ws + WS_DONE);
    int*   vdone   = (int*)((char*)d_ws + WS_VDONE);
    int*   pcnt    = (int*)((char*)d_ws + WS_PCNT);
    unsigned short* faces = (unsigned short*)((char*)d_ws + WS_HDR);

    size_t per_vol = (size_t)FACES_PER_VOL * 2
                   + (size_t)NPAIRS * SEGCAP * 4
                   + (size_t)FALLR * 4;
    size_t avail   = (ws_size > WS_HDR) ? ws_size - WS_HDR : 0;
    int vols_per_pass = (int)(avail / per_vol);
    if (vols_per_pass > NVOL) vols_per_pass = NVOL;
    if (vols_per_pass < 1) vols_per_pass = 1;
    unsigned* pairs = (unsigned*)(faces + (size_t)vols_per_pass * FACES_PER_VOL);
    int* gfall = (int*)(pairs + (size_t)vols_per_pass * NPAIRS * SEGCAP);

    hipMemsetAsync(d_ws, 0, WS_HDR, stream);

    for (int vbase = 0; vbase < NVOL; vbase += vols_per_pass) {
        int nv = NVOL - vbase;
        if (nv > vols_per_pass) nv = vols_per_pass;
        dim3 tgrid(TILES_W * TILES_H, nv);
        ccl_local<<<tgrid, dim3(256), 0, stream>>>(pred, targ, faces,
                                                   rootcnt, acc, vbase);
        dim3 mgrid(NPAIRS, nv);
        ccl_bmerge<<<mgrid, dim3(1024), 0, stream>>>(faces, pairs, pcnt, gfall,
                                                     rootcnt, comp, done, vdone,
                                                     acc, out, vbase);
    }
}